// Round 6
// baseline (542.008 us; speedup 1.0000x reference)
//
#include <hip/hip_runtime.h>

#define S_LEN 2048

typedef __attribute__((ext_vector_type(8))) short short8;
typedef __attribute__((ext_vector_type(4))) float f32x4;
typedef __attribute__((ext_vector_type(2))) unsigned int u32x2;
typedef unsigned short u16;
typedef unsigned int u32;
typedef __attribute__((ext_vector_type(4))) unsigned short us4;

__device__ __forceinline__ u16 f2bf(float f) {
  union { float f; u32 u; } v; v.f = f;
  u32 r = v.u + 0x7FFFu + ((v.u >> 16) & 1u);
  return (u16)(r >> 16);
}

// packed f32x2 -> bf16x2 (RNE), 1 VALU inst
__device__ __forceinline__ u32 cvtpk(float lo, float hi) {
  u32 r;
  asm("v_cvt_pk_bf16_f32 %0, %1, %2" : "=v"(r) : "v"(lo), "v"(hi));
  return r;
}

__device__ __forceinline__ void gload_lds16(const u16* g, u16* l) {
  __builtin_amdgcn_global_load_lds(
      (const __attribute__((address_space(1))) u32*)g,
      (__attribute__((address_space(3))) u32*)l, 16, 0, 0);
}

__device__ __forceinline__ f32x4 mfma16(short8 a, short8 b, f32x4 c) {
  return __builtin_amdgcn_mfma_f32_16x16x32_bf16(a, b, c, 0, 0, 0);
}

// Stage NL*256 16B-units of an 8-unit-per-row tile into linear LDS with
// 3-bit row-XOR source pre-swizzle (linear dest + inverse-swz source).
template <int NL>
__device__ __forceinline__ void stage8(const u16* __restrict__ gbase, int row_stride,
                                       u16* lds, int tid) {
#pragma unroll
  for (int p = 0; p < NL; ++p) {
    int L = tid + p * 256;
    int r = L >> 3, up = L & 7;
    int u = up ^ (r & 7);
    gload_lds16(gbase + (size_t)r * row_stride + u * 8, lds + (size_t)L * 8);
  }
}
__device__ __forceinline__ short8 ldsfrag8(const u16* lds, int row, int u) {
  int up = u ^ (row & 7);
  return *(const short8*)(lds + (size_t)row * 64 + up * 8);
}

// ---------------- convert f32 -> bf16 (x, in_proj_w, out_proj_w) ----------------
__global__ __launch_bounds__(256) void convert_kernel(
    const float* __restrict__ x, const float* __restrict__ wi, const float* __restrict__ wo,
    u16* __restrict__ xbf, u16* __restrict__ wibf, u16* __restrict__ wobf) {
  int idx = blockIdx.x * 256 + threadIdx.x;   // each handles 4 floats
  const float* src; u16* dst; int off;
  if (idx < 2097152)            { src = x;  dst = xbf;  off = idx; }
  else if (idx < 2883584)       { src = wi; dst = wibf; off = idx - 2097152; }
  else                          { src = wo; dst = wobf; off = idx - 2883584; }
  f32x4 v = *(const f32x4*)(src + (size_t)off * 4);
  us4 r;
#pragma unroll
  for (int j = 0; j < 4; ++j) r[j] = f2bf(v[j]);
  *(us4*)(dst + (size_t)off * 4) = r;
}

// ---------------- shared 128x128 GEMM core: C = A[M,K] * B[N,K]^T ----------------
__device__ __forceinline__ void gemm_core(const u16* __restrict__ A, const u16* __restrict__ B,
                                          int m0, int n0, int K,
                                          u16* aL, u16* bL, f32x4 acc[4][4]) {
  const int tid = threadIdx.x;
  const int lane = tid & 63, w = tid >> 6;
  const int l15 = lane & 15, g = lane >> 4;
  const int wr = w >> 1, wc = w & 1;
#pragma unroll
  for (int i = 0; i < 4; ++i)
#pragma unroll
    for (int n = 0; n < 4; ++n) acc[i][n] = (f32x4){0.f, 0.f, 0.f, 0.f};
  const int nK = K >> 6;
  stage8<4>(A + (size_t)m0 * K, K, aL, tid);
  stage8<4>(B + (size_t)n0 * K, K, bL, tid);
  __syncthreads();
  int buf = 0;
  for (int kt = 0; kt < nK; ++kt) {
    if (kt + 1 < nK) {
      stage8<4>(A + (size_t)m0 * K + (kt + 1) * 64, K, aL + (buf ^ 1) * 8192, tid);
      stage8<4>(B + (size_t)n0 * K + (kt + 1) * 64, K, bL + (buf ^ 1) * 8192, tid);
    }
    const u16* ab = aL + buf * 8192;
    const u16* bb = bL + buf * 8192;
#pragma unroll
    for (int ks = 0; ks < 2; ++ks) {
      short8 af[4], bf[4];
#pragma unroll
      for (int i = 0; i < 4; ++i) af[i] = ldsfrag8(ab, wr * 64 + i * 16 + l15, ks * 4 + g);
#pragma unroll
      for (int n = 0; n < 4; ++n) bf[n] = ldsfrag8(bb, wc * 64 + n * 16 + l15, ks * 4 + g);
      __builtin_amdgcn_s_setprio(1);
#pragma unroll
      for (int i = 0; i < 4; ++i)
#pragma unroll
        for (int n = 0; n < 4; ++n)
          acc[i][n] = mfma16(af[i], bf[n], acc[i][n]);
      __builtin_amdgcn_s_setprio(0);
    }
    __syncthreads();
    buf ^= 1;
  }
}

// XCD-bijective remap (requires nwg % 8 == 0)
__device__ __forceinline__ void xcd_remap(int& m0, int& n0) {
  int id = blockIdx.y * gridDim.x + blockIdx.x;
  int nwg = gridDim.x * gridDim.y;
  int nid = (id & 7) * (nwg >> 3) + (id >> 3);
  m0 = (nid % gridDim.x) * 128;
  n0 = (nid / gridDim.x) * 128;
}

// ---------------- GEMM1: qkv = x @ W_in^T + b; scatter to [3][BH][S][64] bf16 ----------------
// q additionally scaled by hd^-0.5 * log2(e)  (folds softmax's base-2 conversion)
__global__ __launch_bounds__(256, 2) void gemm_qkv_kernel(
    const u16* __restrict__ xbf, const u16* __restrict__ wbf,
    const float* __restrict__ bias, u16* __restrict__ qkv) {
  __shared__ u16 aL[2 * 8192];
  __shared__ u16 bL[2 * 8192];
  f32x4 acc[4][4];
  int m0, n0;
  xcd_remap(m0, n0);
  gemm_core(xbf, wbf, m0, n0, 1024, aL, bL, acc);
  const int tid = threadIdx.x, lane = tid & 63, w = tid >> 6;
  const int l15 = lane & 15, g = lane >> 4;
  const int wr = w >> 1, wc = w & 1;
  const int sec = n0 >> 10;                        // 0=q 1=k 2=v
  u16* dst = qkv + (size_t)sec * 8388608;
  const float scale = (sec == 0) ? 0.18033688011112042f : 1.0f;  // 0.125*log2(e)
#pragma unroll
  for (int n = 0; n < 4; ++n) {
    int ng = n0 + wc * 64 + n * 16 + l15;
    float bv = bias[ng];
    int e = ng & 1023, h = e >> 6, d = e & 63;
#pragma unroll
    for (int i = 0; i < 4; ++i)
#pragma unroll
      for (int j = 0; j < 4; ++j) {
        int mg = m0 + wr * 64 + i * 16 + g * 4 + j;
        int s = mg >> 2, b = mg & 3;
        float c = (acc[i][n][j] + bv) * scale;
        dst[(((size_t)(b * 16 + h)) * 2048 + s) * 64 + d] = f2bf(c);
      }
  }
}

// ---------------- transpose V: [BH][2048][64] -> [BH][64][2048] ----------------
__global__ __launch_bounds__(256) void transpose_v_kernel(const u16* __restrict__ v,
                                                          u16* __restrict__ vt) {
  __shared__ u16 t[64 * 72];
  const int bh = blockIdx.x, sb = blockIdx.y;
  const int tid = threadIdx.x;
  const u16* vb = v + (((size_t)bh * 2048) + sb * 64) * 64;
#pragma unroll
  for (int p = 0; p < 2; ++p) {
    int L = tid + p * 256;
    int r = L >> 3, u = L & 7;
    *(short8*)(t + r * 72 + u * 8) = *(const short8*)(vb + (size_t)r * 64 + u * 8);
  }
  __syncthreads();
  const int d = tid >> 2, sc = (tid & 3) * 16;
  u16 buf[16];
#pragma unroll
  for (int q2 = 0; q2 < 16; ++q2) buf[q2] = t[(sc + q2) * 72 + d];
  u16* dst = vt + (size_t)bh * 131072 + (size_t)d * 2048 + sb * 64 + sc;
  *(short8*)(dst) = *(short8*)(buf);
  *(short8*)(dst + 8) = *(short8*)(buf + 8);
}

// ---------------- fused attention: 2-pass flash (no max: scores bounded) ----------------
// Swapped QK^T: acc[i][n][j] = S[q = w*32+i*16+l15][k = n*16+g*4+j] (log2-domain, q pre-scaled)
// LDS pool (48 KB -> 3 blocks/CU):
//   pass 1: K[128][64] dbuf @ 0, 8192 (u16 units)
//   pass 2: K[64][64] dbuf @ buf*4096; V^T[64][64] dbuf @ 8192+buf*4096; P @ 16384+w*2048
__global__ __launch_bounds__(256, 3) void attn_kernel(
    const u16* __restrict__ qkv, const u16* __restrict__ vt,
    float* __restrict__ attn, u16* __restrict__ ows) {
  __shared__ u16 lds[24576];
  const int tid = threadIdx.x, w = tid >> 6, lane = tid & 63;
  const int l15 = lane & 15, g = lane >> 4;
  const int qb = blockIdx.x, bh = blockIdx.y;
  const int q0 = qb * 128;
  const u16* qbase = qkv + (size_t)bh * 131072;
  const u16* kbase = qkv + 8388608 + (size_t)bh * 131072;
  const u16* vtb = vt + (size_t)bh * 131072;

  short8 qf[2][2];
#pragma unroll
  for (int i = 0; i < 2; ++i)
#pragma unroll
    for (int ks = 0; ks < 2; ++ks)
      qf[i][ks] = *(const short8*)(qbase + ((size_t)(q0 + w * 32 + i * 16 + l15)) * 64 + ks * 32 + g * 8);

  // ---- pass 1: row sum of exp2(S), KVBLK=128, single barrier per kt ----
  float lsum[2] = {0.f, 0.f};
  stage8<4>(kbase, 64, lds, tid);
  __syncthreads();
  int buf = 0;
  for (int kt = 0; kt < 16; ++kt) {
    if (kt < 15) stage8<4>(kbase + (size_t)(kt + 1) * 8192, 64, lds + (buf ^ 1) * 8192, tid);
    const u16* kb = lds + buf * 8192;
    f32x4 acc[2][8];
#pragma unroll
    for (int i = 0; i < 2; ++i)
#pragma unroll
      for (int n = 0; n < 8; ++n) acc[i][n] = (f32x4){0.f, 0.f, 0.f, 0.f};
#pragma unroll
    for (int ks = 0; ks < 2; ++ks) {
      short8 kf[8];
#pragma unroll
      for (int n = 0; n < 8; ++n) kf[n] = ldsfrag8(kb, n * 16 + l15, ks * 4 + g);
      __builtin_amdgcn_s_setprio(1);
#pragma unroll
      for (int i = 0; i < 2; ++i)
#pragma unroll
        for (int n = 0; n < 8; ++n)
          acc[i][n] = mfma16(kf[n], qf[i][ks], acc[i][n]);
      __builtin_amdgcn_s_setprio(0);
    }
#pragma unroll
    for (int i = 0; i < 2; ++i) {
      f32x4 vs = {0.f, 0.f, 0.f, 0.f};
#pragma unroll
      for (int n = 0; n < 8; ++n)
#pragma unroll
        for (int j = 0; j < 4; ++j)
          vs[j] += __builtin_amdgcn_exp2f(acc[i][n][j]);
      float s = (vs[0] + vs[1]) + (vs[2] + vs[3]);
      s += __shfl_xor(s, 16);
      s += __shfl_xor(s, 32);
      lsum[i] += s;
    }
    __syncthreads();
    buf ^= 1;
  }
  float rl[2] = {1.0f / lsum[0], 1.0f / lsum[1]};

  // ---- pass 2: KVBLK=64; counted-vmcnt barrier lets nt-stores drain across kt ----
  u16* const pw = lds + 16384 + w * 2048;          // per-wave P [32][64] swz8
  f32x4 oacc[2][4];
#pragma unroll
  for (int i = 0; i < 2; ++i)
#pragma unroll
    for (int nd = 0; nd < 4; ++nd) oacc[i][nd] = (f32x4){0.f, 0.f, 0.f, 0.f};
  stage8<2>(kbase, 64, lds, tid);
  stage8<2>(vtb, 2048, lds + 8192, tid);
  __syncthreads();
  buf = 0;
  float* arow = attn + ((size_t)bh * 2048 + q0 + w * 32) * 2048;
  for (int kt = 0; kt < 32; ++kt) {
    const u16* kb = lds + buf * 4096;
    const u16* vb = lds + 8192 + buf * 4096;
    // stage loads FIRST (oldest in vmcnt FIFO; retired by the counted wait below)
    if (kt < 31) {
      stage8<2>(kbase + (size_t)(kt + 1) * 4096, 64, lds + (buf ^ 1) * 4096, tid);
      stage8<2>(vtb + (size_t)(kt + 1) * 64, 2048, lds + 8192 + (buf ^ 1) * 4096, tid);
    }
    f32x4 acc[2][4];
#pragma unroll
    for (int i = 0; i < 2; ++i)
#pragma unroll
      for (int n = 0; n < 4; ++n) acc[i][n] = (f32x4){0.f, 0.f, 0.f, 0.f};
#pragma unroll
    for (int ks = 0; ks < 2; ++ks) {
      short8 kf[4];
#pragma unroll
      for (int n = 0; n < 4; ++n) kf[n] = ldsfrag8(kb, n * 16 + l15, ks * 4 + g);
      __builtin_amdgcn_s_setprio(1);
#pragma unroll
      for (int i = 0; i < 2; ++i)
#pragma unroll
        for (int n = 0; n < 4; ++n)
          acc[i][n] = mfma16(kf[n], qf[i][ks], acc[i][n]);
      __builtin_amdgcn_s_setprio(0);
    }
    // softmax: normalize, nt-store f32 attn (newest in FIFO), pack bf16 P -> LDS
#pragma unroll
    for (int i = 0; i < 2; ++i) {
      const int m = i * 16 + l15;
#pragma unroll
      for (int n = 0; n < 4; ++n) {
        f32x4 p4;
        p4[0] = __builtin_amdgcn_exp2f(acc[i][n][0]) * rl[i];
        p4[1] = __builtin_amdgcn_exp2f(acc[i][n][1]) * rl[i];
        p4[2] = __builtin_amdgcn_exp2f(acc[i][n][2]) * rl[i];
        p4[3] = __builtin_amdgcn_exp2f(acc[i][n][3]) * rl[i];
        __builtin_nontemporal_store(
            p4, (f32x4*)(arow + (size_t)m * 2048 + kt * 64 + n * 16 + g * 4));
        u32x2 pk2;
        pk2[0] = cvtpk(p4[0], p4[1]);
        pk2[1] = cvtpk(p4[2], p4[3]);
        const int up = (n * 2 + (g >> 1)) ^ (m & 7);
        *(u32x2*)(pw + m * 64 + up * 8 + (g & 1) * 4) = pk2;
      }
    }
    // PV: O += P @ V  (pw is per-wave; lgkmcnt ordering handled by compiler)
#pragma unroll
    for (int kp = 0; kp < 2; ++kp) {
      short8 ap[2], vf[4];
#pragma unroll
      for (int i = 0; i < 2; ++i) {
        int row = i * 16 + l15;
        ap[i] = *(const short8*)(pw + row * 64 + (((kp * 4 + g) ^ (row & 7)) * 8));
      }
#pragma unroll
      for (int nd = 0; nd < 4; ++nd) vf[nd] = ldsfrag8(vb, nd * 16 + l15, kp * 4 + g);
      __builtin_amdgcn_s_setprio(1);
#pragma unroll
      for (int i = 0; i < 2; ++i)
#pragma unroll
        for (int nd = 0; nd < 4; ++nd)
          oacc[i][nd] = mfma16(ap[i], vf[nd], oacc[i][nd]);
      __builtin_amdgcn_s_setprio(0);
    }
    // counted wait: retire the 4 stage loads (oldest), leave <=8 nt-stores in flight
    asm volatile("s_waitcnt vmcnt(8) lgkmcnt(0)" ::: "memory");
    __builtin_amdgcn_sched_barrier(0);
    __builtin_amdgcn_s_barrier();
    buf ^= 1;
  }
  // epilogue: O -> ows[(s*4+b)][h*64+d] bf16
  const int b = bh >> 4, h = bh & 15;
#pragma unroll
  for (int i = 0; i < 2; ++i)
#pragma unroll
    for (int nd = 0; nd < 4; ++nd)
#pragma unroll
      for (int j = 0; j < 4; ++j) {
        int qrow = q0 + w * 32 + i * 16 + g * 4 + j;
        int d = nd * 16 + l15;
        ows[((size_t)qrow * 4 + b) * 1024 + (size_t)h * 64 + d] = f2bf(oacc[i][nd][j]);
      }
}

// ---------------- GEMM2: out = O @ W_out^T + b (f32 out) ----------------
__global__ __launch_bounds__(256, 2) void gemm_out_kernel(
    const u16* __restrict__ abf, const u16* __restrict__ wbf,
    const float* __restrict__ bias, float* __restrict__ out) {
  __shared__ u16 aL[2 * 8192];
  __shared__ u16 bL[2 * 8192];
  f32x4 acc[4][4];
  int m0, n0;
  xcd_remap(m0, n0);
  gemm_core(abf, wbf, m0, n0, 1024, aL, bL, acc);
  const int tid = threadIdx.x, lane = tid & 63, w = tid >> 6;
  const int l15 = lane & 15, g = lane >> 4;
  const int wr = w >> 1, wc = w & 1;
#pragma unroll
  for (int n = 0; n < 4; ++n) {
    int ng = n0 + wc * 64 + n * 16 + l15;
    float bv = bias[ng];
#pragma unroll
    for (int i = 0; i < 4; ++i)
#pragma unroll
      for (int j = 0; j < 4; ++j) {
        int mg = m0 + wr * 64 + i * 16 + g * 4 + j;
        out[(size_t)mg * 1024 + ng] = acc[i][n][j] + bv;
      }
  }
}

extern "C" void kernel_launch(void* const* d_in, const int* in_sizes, int n_in,
                              void* d_out, int out_size, void* d_ws, size_t ws_size,
                              hipStream_t stream) {
  const float* x     = (const float*)d_in[0];
  const float* w_in  = (const float*)d_in[1];
  const float* b_in  = (const float*)d_in[2];
  const float* w_out = (const float*)d_in[3];
  const float* b_out = (const float*)d_in[4];
  float* out  = (float*)d_out;
  float* attn = out + 8388608;              // [64][2048][2048]

  char* ws = (char*)d_ws;
  u16* qkv  = (u16*)ws;                      // [3][64][2048][64] bf16
  u16* vt   = (u16*)(ws + 50331648);         // [64][64][2048]
  u16* xbf  = (u16*)(ws + 67108864);         // [8192][1024] (reused as O)
  u16* wibf = (u16*)(ws + 83886080);         // [3072][1024]
  u16* wobf = (u16*)(ws + 90177536);         // [1024][1024]
  u16* ows  = xbf;                           // reuse after gemm1 consumed xbf

  convert_kernel<<<12288, 256, 0, stream>>>(x, w_in, w_out, xbf, wibf, wobf);
  gemm_qkv_kernel<<<dim3(64, 24), 256, 0, stream>>>(xbf, wibf, b_in, qkv);
  transpose_v_kernel<<<dim3(64, 32), 256, 0, stream>>>(qkv + 16777216, vt);
  attn_kernel<<<dim3(16, 64), 256, 0, stream>>>(qkv, vt, attn, ows);
  gemm_out_kernel<<<dim3(64, 8), 256, 0, stream>>>(ows, wobf, b_out, out);
}

// Round 7
// 435.044 us; speedup vs baseline: 1.2459x; 1.2459x over previous
//
#include <hip/hip_runtime.h>

#define S_LEN 2048

typedef __attribute__((ext_vector_type(8))) short short8;
typedef __attribute__((ext_vector_type(4))) float f32x4;
typedef __attribute__((ext_vector_type(2))) unsigned int u32x2;
typedef unsigned short u16;
typedef unsigned int u32;
typedef __attribute__((ext_vector_type(4))) unsigned short us4;

__device__ __forceinline__ u16 f2bf(float f) {
  union { float f; u32 u; } v; v.f = f;
  u32 r = v.u + 0x7FFFu + ((v.u >> 16) & 1u);
  return (u16)(r >> 16);
}

// packed f32x2 -> bf16x2 (RNE), 1 VALU inst
__device__ __forceinline__ u32 cvtpk(float lo, float hi) {
  u32 r;
  asm("v_cvt_pk_bf16_f32 %0, %1, %2" : "=v"(r) : "v"(lo), "v"(hi));
  return r;
}

__device__ __forceinline__ void gload_lds16(const u16* g, u16* l) {
  __builtin_amdgcn_global_load_lds(
      (const __attribute__((address_space(1))) u32*)g,
      (__attribute__((address_space(3))) u32*)l, 16, 0, 0);
}

__device__ __forceinline__ f32x4 mfma16(short8 a, short8 b, f32x4 c) {
  return __builtin_amdgcn_mfma_f32_16x16x32_bf16(a, b, c, 0, 0, 0);
}

// Stage NL*256 16B-units of an 8-unit-per-row tile into linear LDS with
// 3-bit row-XOR source pre-swizzle (linear dest + inverse-swz source).
template <int NL>
__device__ __forceinline__ void stage8(const u16* __restrict__ gbase, int row_stride,
                                       u16* lds, int tid) {
#pragma unroll
  for (int p = 0; p < NL; ++p) {
    int L = tid + p * 256;
    int r = L >> 3, up = L & 7;
    int u = up ^ (r & 7);
    gload_lds16(gbase + (size_t)r * row_stride + u * 8, lds + (size_t)L * 8);
  }
}
__device__ __forceinline__ short8 ldsfrag8(const u16* lds, int row, int u) {
  int up = u ^ (row & 7);
  return *(const short8*)(lds + (size_t)row * 64 + up * 8);
}

// ---------------- convert f32 -> bf16 (x, in_proj_w, out_proj_w) ----------------
__global__ __launch_bounds__(256) void convert_kernel(
    const float* __restrict__ x, const float* __restrict__ wi, const float* __restrict__ wo,
    u16* __restrict__ xbf, u16* __restrict__ wibf, u16* __restrict__ wobf) {
  int idx = blockIdx.x * 256 + threadIdx.x;   // each handles 4 floats
  const float* src; u16* dst; int off;
  if (idx < 2097152)            { src = x;  dst = xbf;  off = idx; }
  else if (idx < 2883584)       { src = wi; dst = wibf; off = idx - 2097152; }
  else                          { src = wo; dst = wobf; off = idx - 2883584; }
  f32x4 v = *(const f32x4*)(src + (size_t)off * 4);
  us4 r;
#pragma unroll
  for (int j = 0; j < 4; ++j) r[j] = f2bf(v[j]);
  *(us4*)(dst + (size_t)off * 4) = r;
}

// ---------------- shared 128x128 GEMM core: C = A[M,K] * B[N,K]^T ----------------
__device__ __forceinline__ void gemm_core(const u16* __restrict__ A, const u16* __restrict__ B,
                                          int m0, int n0, int K,
                                          u16* aL, u16* bL, f32x4 acc[4][4]) {
  const int tid = threadIdx.x;
  const int lane = tid & 63, w = tid >> 6;
  const int l15 = lane & 15, g = lane >> 4;
  const int wr = w >> 1, wc = w & 1;
#pragma unroll
  for (int i = 0; i < 4; ++i)
#pragma unroll
    for (int n = 0; n < 4; ++n) acc[i][n] = (f32x4){0.f, 0.f, 0.f, 0.f};
  const int nK = K >> 6;
  stage8<4>(A + (size_t)m0 * K, K, aL, tid);
  stage8<4>(B + (size_t)n0 * K, K, bL, tid);
  __syncthreads();
  int buf = 0;
  for (int kt = 0; kt < nK; ++kt) {
    if (kt + 1 < nK) {
      stage8<4>(A + (size_t)m0 * K + (kt + 1) * 64, K, aL + (buf ^ 1) * 8192, tid);
      stage8<4>(B + (size_t)n0 * K + (kt + 1) * 64, K, bL + (buf ^ 1) * 8192, tid);
    }
    const u16* ab = aL + buf * 8192;
    const u16* bb = bL + buf * 8192;
#pragma unroll
    for (int ks = 0; ks < 2; ++ks) {
      short8 af[4], bf[4];
#pragma unroll
      for (int i = 0; i < 4; ++i) af[i] = ldsfrag8(ab, wr * 64 + i * 16 + l15, ks * 4 + g);
#pragma unroll
      for (int n = 0; n < 4; ++n) bf[n] = ldsfrag8(bb, wc * 64 + n * 16 + l15, ks * 4 + g);
      __builtin_amdgcn_s_setprio(1);
#pragma unroll
      for (int i = 0; i < 4; ++i)
#pragma unroll
        for (int n = 0; n < 4; ++n)
          acc[i][n] = mfma16(af[i], bf[n], acc[i][n]);
      __builtin_amdgcn_s_setprio(0);
    }
    __syncthreads();
    buf ^= 1;
  }
}

// XCD-bijective remap (requires nwg % 8 == 0)
__device__ __forceinline__ void xcd_remap(int& m0, int& n0) {
  int id = blockIdx.y * gridDim.x + blockIdx.x;
  int nwg = gridDim.x * gridDim.y;
  int nid = (id & 7) * (nwg >> 3) + (id >> 3);
  m0 = (nid % gridDim.x) * 128;
  n0 = (nid / gridDim.x) * 128;
}

// ---------------- GEMM1: qkv = x @ W_in^T + b -> q,k scatter + V^T fused ----------------
// q additionally scaled by hd^-0.5 * log2(e)  (folds softmax's base-2 conversion)
// Epilogue stages C-tile in LDS (128x132 padded bf16), then writes coalesced:
//   sec 0/1 -> qkv[sec][bh][s][64] via short8 (128B segments)
//   sec 2   -> vt[bh][64][2048] directly (fused V-transpose; transpose_v kernel dropped)
__global__ __launch_bounds__(256, 2) void gemm_qkv_kernel(
    const u16* __restrict__ xbf, const u16* __restrict__ wbf,
    const float* __restrict__ bias, u16* __restrict__ qkv, u16* __restrict__ vt) {
  __shared__ u16 pool[32768];          // 64 KB: gemm dbuf; reused as C_lds
  f32x4 acc[4][4];
  int m0, n0;
  xcd_remap(m0, n0);
  gemm_core(xbf, wbf, m0, n0, 1024, pool, pool + 16384, acc);
  const int tid = threadIdx.x, lane = tid & 63, w = tid >> 6;
  const int l15 = lane & 15, g = lane >> 4;
  const int wr = w >> 1, wc = w & 1;
  const int sec = n0 >> 10;                        // 0=q 1=k 2=v
  const float scale = (sec == 0) ? 0.18033688011112042f : 1.0f;  // 0.125*log2(e)
  // acc -> C_lds (padded stride 132 breaks bank conflicts for strided gathers)
  u16* cl = pool;
#pragma unroll
  for (int n = 0; n < 4; ++n) {
    int c = wc * 64 + n * 16 + l15;
    float bv = bias[n0 + c];
#pragma unroll
    for (int i = 0; i < 4; ++i)
#pragma unroll
      for (int j = 0; j < 4; ++j) {
        int mrow = wr * 64 + i * 16 + g * 4 + j;
        cl[mrow * 132 + c] = f2bf((acc[i][n][j] + bv) * scale);
      }
  }
  __syncthreads();
  const int h0 = (n0 & 1023) >> 6;
  if (sec < 2) {
    u16* dst = qkv + (size_t)sec * 8388608;
#pragma unroll
    for (int rep = 0; rep < 8; ++rep) {
      int chunk = rep * 256 + tid;
      int mrow = chunk >> 4, c = (chunk & 15) << 3;
      short8 vv = *(const short8*)(cl + mrow * 132 + c);
      int mg = m0 + mrow;
      int s = mg >> 2, b = mg & 3;
      int h = h0 + (c >> 6), d = c & 63;
      *(short8*)(dst + (((size_t)(b * 16 + h)) * 2048 + s) * 64 + d) = vv;
    }
  } else {
#pragma unroll
    for (int rep = 0; rep < 8; ++rep) {
      int chunk = rep * 256 + tid;
      int col = chunk >> 4;
      int b = (chunk >> 2) & 3;
      int sc = (chunk & 3) << 3;
      short8 vv;
#pragma unroll
      for (int t = 0; t < 8; ++t)
        vv[t] = (short)cl[(((sc + t) << 2) | b) * 132 + col];
      int h = h0 + (col >> 6), d = col & 63;
      *(short8*)(vt + (size_t)(b * 16 + h) * 131072 + (size_t)d * 2048 + (m0 >> 2) + sc) = vv;
    }
  }
}

// ---------------- fused attention: 2-pass flash (no max: scores bounded) ----------------
// Swapped QK^T: acc[i][n][j] = S[q = w*32+i*16+l15][k = n*16+g*4+j] (log2-domain, q pre-scaled)
// LDS pool (48 KB -> 3 blocks/CU):
//   pass 1: K[128][64] dbuf @ 0, 8192 (u16 units)
//   pass 2: K[64][64] dbuf @ buf*4096; V^T[64][64] dbuf @ 8192+buf*4096; P @ 16384+w*2048
__global__ __launch_bounds__(256, 3) void attn_kernel(
    const u16* __restrict__ qkv, const u16* __restrict__ vt,
    float* __restrict__ attn, u16* __restrict__ ows) {
  __shared__ u16 lds[24576];
  const int tid = threadIdx.x, w = tid >> 6, lane = tid & 63;
  const int l15 = lane & 15, g = lane >> 4;
  const int qb = blockIdx.x, bh = blockIdx.y;
  const int q0 = qb * 128;
  const u16* qbase = qkv + (size_t)bh * 131072;
  const u16* kbase = qkv + 8388608 + (size_t)bh * 131072;
  const u16* vtb = vt + (size_t)bh * 131072;

  short8 qf[2][2];
#pragma unroll
  for (int i = 0; i < 2; ++i)
#pragma unroll
    for (int ks = 0; ks < 2; ++ks)
      qf[i][ks] = *(const short8*)(qbase + ((size_t)(q0 + w * 32 + i * 16 + l15)) * 64 + ks * 32 + g * 8);

  // ---- pass 1: row sum of exp2(S), KVBLK=128, single barrier per kt ----
  float lsum[2] = {0.f, 0.f};
  stage8<4>(kbase, 64, lds, tid);
  __syncthreads();
  int buf = 0;
  for (int kt = 0; kt < 16; ++kt) {
    if (kt < 15) stage8<4>(kbase + (size_t)(kt + 1) * 8192, 64, lds + (buf ^ 1) * 8192, tid);
    const u16* kb = lds + buf * 8192;
    f32x4 acc[2][8];
#pragma unroll
    for (int i = 0; i < 2; ++i)
#pragma unroll
      for (int n = 0; n < 8; ++n) acc[i][n] = (f32x4){0.f, 0.f, 0.f, 0.f};
#pragma unroll
    for (int ks = 0; ks < 2; ++ks) {
      short8 kf[8];
#pragma unroll
      for (int n = 0; n < 8; ++n) kf[n] = ldsfrag8(kb, n * 16 + l15, ks * 4 + g);
      __builtin_amdgcn_s_setprio(1);
#pragma unroll
      for (int i = 0; i < 2; ++i)
#pragma unroll
        for (int n = 0; n < 8; ++n)
          acc[i][n] = mfma16(kf[n], qf[i][ks], acc[i][n]);
      __builtin_amdgcn_s_setprio(0);
    }
#pragma unroll
    for (int i = 0; i < 2; ++i) {
      f32x4 vs = {0.f, 0.f, 0.f, 0.f};
#pragma unroll
      for (int n = 0; n < 8; ++n)
#pragma unroll
        for (int j = 0; j < 4; ++j)
          vs[j] += __builtin_amdgcn_exp2f(acc[i][n][j]);
      float s = (vs[0] + vs[1]) + (vs[2] + vs[3]);
      s += __shfl_xor(s, 16);
      s += __shfl_xor(s, 32);
      lsum[i] += s;
    }
    __syncthreads();
    buf ^= 1;
  }
  float rl[2] = {1.0f / lsum[0], 1.0f / lsum[1]};

  // ---- pass 2: KVBLK=64, single barrier per kt; regular (L2-merged) attn stores ----
  u16* const pw = lds + 16384 + w * 2048;          // per-wave P [32][64] swz8
  f32x4 oacc[2][4];
#pragma unroll
  for (int i = 0; i < 2; ++i)
#pragma unroll
    for (int nd = 0; nd < 4; ++nd) oacc[i][nd] = (f32x4){0.f, 0.f, 0.f, 0.f};
  stage8<2>(kbase, 64, lds, tid);
  stage8<2>(vtb, 2048, lds + 8192, tid);
  __syncthreads();
  buf = 0;
  float* arow = attn + ((size_t)bh * 2048 + q0 + w * 32) * 2048;
  for (int kt = 0; kt < 32; ++kt) {
    const u16* kb = lds + buf * 4096;
    const u16* vb = lds + 8192 + buf * 4096;
    if (kt < 31) {
      stage8<2>(kbase + (size_t)(kt + 1) * 4096, 64, lds + (buf ^ 1) * 4096, tid);
      stage8<2>(vtb + (size_t)(kt + 1) * 64, 2048, lds + 8192 + (buf ^ 1) * 4096, tid);
    }
    f32x4 acc[2][4];
#pragma unroll
    for (int i = 0; i < 2; ++i)
#pragma unroll
      for (int n = 0; n < 4; ++n) acc[i][n] = (f32x4){0.f, 0.f, 0.f, 0.f};
#pragma unroll
    for (int ks = 0; ks < 2; ++ks) {
      short8 kf[4];
#pragma unroll
      for (int n = 0; n < 4; ++n) kf[n] = ldsfrag8(kb, n * 16 + l15, ks * 4 + g);
      __builtin_amdgcn_s_setprio(1);
#pragma unroll
      for (int i = 0; i < 2; ++i)
#pragma unroll
        for (int n = 0; n < 4; ++n)
          acc[i][n] = mfma16(kf[n], qf[i][ks], acc[i][n]);
      __builtin_amdgcn_s_setprio(0);
    }
    // softmax: normalize, store f32 attn (via L2 write-merge), pack bf16 P -> LDS
#pragma unroll
    for (int i = 0; i < 2; ++i) {
      const int m = i * 16 + l15;
#pragma unroll
      for (int n = 0; n < 4; ++n) {
        f32x4 p4;
        p4[0] = __builtin_amdgcn_exp2f(acc[i][n][0]) * rl[i];
        p4[1] = __builtin_amdgcn_exp2f(acc[i][n][1]) * rl[i];
        p4[2] = __builtin_amdgcn_exp2f(acc[i][n][2]) * rl[i];
        p4[3] = __builtin_amdgcn_exp2f(acc[i][n][3]) * rl[i];
        *(f32x4*)(arow + (size_t)m * 2048 + kt * 64 + n * 16 + g * 4) = p4;
        u32x2 pk2;
        pk2[0] = cvtpk(p4[0], p4[1]);
        pk2[1] = cvtpk(p4[2], p4[3]);
        const int up = (n * 2 + (g >> 1)) ^ (m & 7);
        *(u32x2*)(pw + m * 64 + up * 8 + (g & 1) * 4) = pk2;
      }
    }
    // PV: O += P @ V  (pw is per-wave; lgkmcnt ordering handled by compiler)
#pragma unroll
    for (int kp = 0; kp < 2; ++kp) {
      short8 ap[2], vf[4];
#pragma unroll
      for (int i = 0; i < 2; ++i) {
        int row = i * 16 + l15;
        ap[i] = *(const short8*)(pw + row * 64 + (((kp * 4 + g) ^ (row & 7)) * 8));
      }
#pragma unroll
      for (int nd = 0; nd < 4; ++nd) vf[nd] = ldsfrag8(vb, nd * 16 + l15, kp * 4 + g);
      __builtin_amdgcn_s_setprio(1);
#pragma unroll
      for (int i = 0; i < 2; ++i)
#pragma unroll
        for (int nd = 0; nd < 4; ++nd)
          oacc[i][nd] = mfma16(ap[i], vf[nd], oacc[i][nd]);
      __builtin_amdgcn_s_setprio(0);
    }
    __syncthreads();      // one barrier/kt
    buf ^= 1;
  }
  // epilogue: O -> ows[(s*4+b)][h*64+d] bf16
  const int b = bh >> 4, h = bh & 15;
#pragma unroll
  for (int i = 0; i < 2; ++i)
#pragma unroll
    for (int nd = 0; nd < 4; ++nd)
#pragma unroll
      for (int j = 0; j < 4; ++j) {
        int qrow = q0 + w * 32 + i * 16 + g * 4 + j;
        int d = nd * 16 + l15;
        ows[((size_t)qrow * 4 + b) * 1024 + (size_t)h * 64 + d] = f2bf(oacc[i][nd][j]);
      }
}

// ---------------- GEMM2: out = O @ W_out^T + b (f32 out) ----------------
__global__ __launch_bounds__(256, 2) void gemm_out_kernel(
    const u16* __restrict__ abf, const u16* __restrict__ wbf,
    const float* __restrict__ bias, float* __restrict__ out) {
  __shared__ u16 pool[32768];
  f32x4 acc[4][4];
  int m0, n0;
  xcd_remap(m0, n0);
  gemm_core(abf, wbf, m0, n0, 1024, pool, pool + 16384, acc);
  const int tid = threadIdx.x, lane = tid & 63, w = tid >> 6;
  const int l15 = lane & 15, g = lane >> 4;
  const int wr = w >> 1, wc = w & 1;
#pragma unroll
  for (int n = 0; n < 4; ++n) {
    int ng = n0 + wc * 64 + n * 16 + l15;
    float bv = bias[ng];
#pragma unroll
    for (int i = 0; i < 4; ++i)
#pragma unroll
      for (int j = 0; j < 4; ++j) {
        int mg = m0 + wr * 64 + i * 16 + g * 4 + j;
        out[(size_t)mg * 1024 + ng] = acc[i][n][j] + bv;
      }
  }
}

extern "C" void kernel_launch(void* const* d_in, const int* in_sizes, int n_in,
                              void* d_out, int out_size, void* d_ws, size_t ws_size,
                              hipStream_t stream) {
  const float* x     = (const float*)d_in[0];
  const float* w_in  = (const float*)d_in[1];
  const float* b_in  = (const float*)d_in[2];
  const float* w_out = (const float*)d_in[3];
  const float* b_out = (const float*)d_in[4];
  float* out  = (float*)d_out;
  float* attn = out + 8388608;              // [64][2048][2048]

  char* ws = (char*)d_ws;
  u16* qkv  = (u16*)ws;                      // [2][64][2048][64] bf16 (q,k)
  u16* vt   = (u16*)(ws + 50331648);         // [64][64][2048]
  u16* xbf  = (u16*)(ws + 67108864);         // [8192][1024] (reused as O)
  u16* wibf = (u16*)(ws + 83886080);         // [3072][1024]
  u16* wobf = (u16*)(ws + 90177536);         // [1024][1024]
  u16* ows  = xbf;                           // reuse after gemm1 consumed xbf

  convert_kernel<<<12288, 256, 0, stream>>>(x, w_in, w_out, xbf, wibf, wobf);
  gemm_qkv_kernel<<<dim3(64, 24), 256, 0, stream>>>(xbf, wibf, b_in, qkv, vt);
  attn_kernel<<<dim3(16, 64), 256, 0, stream>>>(qkv, vt, attn, ows);
  gemm_out_kernel<<<dim3(64, 8), 256, 0, stream>>>(ows, wobf, b_out, out);
}

// Round 8
// 390.758 us; speedup vs baseline: 1.3871x; 1.1133x over previous
//
#include <hip/hip_runtime.h>

#define S_LEN 2048

typedef __attribute__((ext_vector_type(8))) short short8;
typedef __attribute__((ext_vector_type(4))) float f32x4;
typedef __attribute__((ext_vector_type(2))) unsigned int u32x2;
typedef unsigned short u16;
typedef unsigned int u32;
typedef __attribute__((ext_vector_type(4))) unsigned short us4;

__device__ __forceinline__ u16 f2bf(float f) {
  union { float f; u32 u; } v; v.f = f;
  u32 r = v.u + 0x7FFFu + ((v.u >> 16) & 1u);
  return (u16)(r >> 16);
}

// packed f32x2 -> bf16x2 (RNE), 1 VALU inst
__device__ __forceinline__ u32 cvtpk(float lo, float hi) {
  u32 r;
  asm("v_cvt_pk_bf16_f32 %0, %1, %2" : "=v"(r) : "v"(lo), "v"(hi));
  return r;
}

__device__ __forceinline__ void gload_lds16(const u16* g, u16* l) {
  __builtin_amdgcn_global_load_lds(
      (const __attribute__((address_space(1))) u32*)g,
      (__attribute__((address_space(3))) u32*)l, 16, 0, 0);
}

__device__ __forceinline__ f32x4 mfma16(short8 a, short8 b, f32x4 c) {
  return __builtin_amdgcn_mfma_f32_16x16x32_bf16(a, b, c, 0, 0, 0);
}

// Stage NL*256 16B-units of an 8-unit-per-row tile into linear LDS with
// 3-bit row-XOR source pre-swizzle (linear dest + inverse-swz source).
template <int NL>
__device__ __forceinline__ void stage8(const u16* __restrict__ gbase, int row_stride,
                                       u16* lds, int tid) {
#pragma unroll
  for (int p = 0; p < NL; ++p) {
    int L = tid + p * 256;
    int r = L >> 3, up = L & 7;
    int u = up ^ (r & 7);
    gload_lds16(gbase + (size_t)r * row_stride + u * 8, lds + (size_t)L * 8);
  }
}
__device__ __forceinline__ short8 ldsfrag8(const u16* lds, int row, int u) {
  int up = u ^ (row & 7);
  return *(const short8*)(lds + (size_t)row * 64 + up * 8);
}

// ---------------- convert f32 -> bf16 (x, in_proj_w, out_proj_w) ----------------
__global__ __launch_bounds__(256) void convert_kernel(
    const float* __restrict__ x, const float* __restrict__ wi, const float* __restrict__ wo,
    u16* __restrict__ xbf, u16* __restrict__ wibf, u16* __restrict__ wobf) {
  int idx = blockIdx.x * 256 + threadIdx.x;   // each handles 4 floats
  const float* src; u16* dst; int off;
  if (idx < 2097152)            { src = x;  dst = xbf;  off = idx; }
  else if (idx < 2883584)       { src = wi; dst = wibf; off = idx - 2097152; }
  else                          { src = wo; dst = wobf; off = idx - 2883584; }
  f32x4 v = *(const f32x4*)(src + (size_t)off * 4);
  us4 r;
#pragma unroll
  for (int j = 0; j < 4; ++j) r[j] = f2bf(v[j]);
  *(us4*)(dst + (size_t)off * 4) = r;
}

// ---------------- shared 128x128 GEMM core: C = A[M,K] * B[N,K]^T ----------------
__device__ __forceinline__ void gemm_core(const u16* __restrict__ A, const u16* __restrict__ B,
                                          int m0, int n0, int K,
                                          u16* aL, u16* bL, f32x4 acc[4][4]) {
  const int tid = threadIdx.x;
  const int lane = tid & 63, w = tid >> 6;
  const int l15 = lane & 15, g = lane >> 4;
  const int wr = w >> 1, wc = w & 1;
#pragma unroll
  for (int i = 0; i < 4; ++i)
#pragma unroll
    for (int n = 0; n < 4; ++n) acc[i][n] = (f32x4){0.f, 0.f, 0.f, 0.f};
  const int nK = K >> 6;
  stage8<4>(A + (size_t)m0 * K, K, aL, tid);
  stage8<4>(B + (size_t)n0 * K, K, bL, tid);
  __syncthreads();
  int buf = 0;
  for (int kt = 0; kt < nK; ++kt) {
    if (kt + 1 < nK) {
      stage8<4>(A + (size_t)m0 * K + (kt + 1) * 64, K, aL + (buf ^ 1) * 8192, tid);
      stage8<4>(B + (size_t)n0 * K + (kt + 1) * 64, K, bL + (buf ^ 1) * 8192, tid);
    }
    const u16* ab = aL + buf * 8192;
    const u16* bb = bL + buf * 8192;
#pragma unroll
    for (int ks = 0; ks < 2; ++ks) {
      short8 af[4], bf[4];
#pragma unroll
      for (int i = 0; i < 4; ++i) af[i] = ldsfrag8(ab, wr * 64 + i * 16 + l15, ks * 4 + g);
#pragma unroll
      for (int n = 0; n < 4; ++n) bf[n] = ldsfrag8(bb, wc * 64 + n * 16 + l15, ks * 4 + g);
      __builtin_amdgcn_s_setprio(1);
#pragma unroll
      for (int i = 0; i < 4; ++i)
#pragma unroll
        for (int n = 0; n < 4; ++n)
          acc[i][n] = mfma16(af[i], bf[n], acc[i][n]);
      __builtin_amdgcn_s_setprio(0);
    }
    __syncthreads();
    buf ^= 1;
  }
}

// XCD-bijective remap (requires nwg % 8 == 0)
__device__ __forceinline__ void xcd_remap(int& m0, int& n0) {
  int id = blockIdx.y * gridDim.x + blockIdx.x;
  int nwg = gridDim.x * gridDim.y;
  int nid = (id & 7) * (nwg >> 3) + (id >> 3);
  m0 = (nid % gridDim.x) * 128;
  n0 = (nid / gridDim.x) * 128;
}

// ---------------- GEMM1: qkv = x @ W_in^T + b -> q,k scatter + V^T fused ----------------
// q additionally scaled by hd^-0.5 * log2(e)  (folds softmax's base-2 conversion)
__global__ __launch_bounds__(256, 2) void gemm_qkv_kernel(
    const u16* __restrict__ xbf, const u16* __restrict__ wbf,
    const float* __restrict__ bias, u16* __restrict__ qkv, u16* __restrict__ vt) {
  __shared__ u16 pool[32768];          // 64 KB: gemm dbuf; reused as C_lds
  f32x4 acc[4][4];
  int m0, n0;
  xcd_remap(m0, n0);
  gemm_core(xbf, wbf, m0, n0, 1024, pool, pool + 16384, acc);
  const int tid = threadIdx.x, lane = tid & 63, w = tid >> 6;
  const int l15 = lane & 15, g = lane >> 4;
  const int wr = w >> 1, wc = w & 1;
  const int sec = n0 >> 10;                        // 0=q 1=k 2=v
  const float scale = (sec == 0) ? 0.18033688011112042f : 1.0f;  // 0.125*log2(e)
  u16* cl = pool;
#pragma unroll
  for (int n = 0; n < 4; ++n) {
    int c = wc * 64 + n * 16 + l15;
    float bv = bias[n0 + c];
#pragma unroll
    for (int i = 0; i < 4; ++i)
#pragma unroll
      for (int j = 0; j < 4; ++j) {
        int mrow = wr * 64 + i * 16 + g * 4 + j;
        cl[mrow * 132 + c] = f2bf((acc[i][n][j] + bv) * scale);
      }
  }
  __syncthreads();
  const int h0 = (n0 & 1023) >> 6;
  if (sec < 2) {
    u16* dst = qkv + (size_t)sec * 8388608;
#pragma unroll
    for (int rep = 0; rep < 8; ++rep) {
      int chunk = rep * 256 + tid;
      int mrow = chunk >> 4, c = (chunk & 15) << 3;
      short8 vv = *(const short8*)(cl + mrow * 132 + c);
      int mg = m0 + mrow;
      int s = mg >> 2, b = mg & 3;
      int h = h0 + (c >> 6), d = c & 63;
      *(short8*)(dst + (((size_t)(b * 16 + h)) * 2048 + s) * 64 + d) = vv;
    }
  } else {
#pragma unroll
    for (int rep = 0; rep < 8; ++rep) {
      int chunk = rep * 256 + tid;
      int col = chunk >> 4;
      int b = (chunk >> 2) & 3;
      int sc = (chunk & 3) << 3;
      short8 vv;
#pragma unroll
      for (int t = 0; t < 8; ++t)
        vv[t] = (short)cl[(((sc + t) << 2) | b) * 132 + col];
      int h = h0 + (col >> 6), d = col & 63;
      *(short8*)(vt + (size_t)(b * 16 + h) * 131072 + (size_t)d * 2048 + (m0 >> 2) + sc) = vv;
    }
  }
}

// ---------------- fused attention ----------------
// Swapped QK^T: acc[i][n][j] = S[q = w*32+i*16+l15][k = n*16+g*4+j] (log2-domain, q pre-scaled)
// pass 1 (KVBLK=64): QK + exp2 + lsum + PV with UNNORMALIZED P (flash late-norm);
//   then O *= 1/l (shuffled to PV row layout) and stored -> no oacc live in pass 2.
// pass 2 (KVBLK=128): pure store stream: QK + exp2*rl + f32 attn store. K-only dbuf.
// LDS: pass1 K dbuf @0/4096, V dbuf @8192/12288, P @16384+w*2048 (48 KB, 3 blk/CU);
//      pass2 reuses @0..16384 as K[128][64] dbuf.
__global__ __launch_bounds__(256, 3) void attn_kernel(
    const u16* __restrict__ qkv, const u16* __restrict__ vt,
    float* __restrict__ attn, u16* __restrict__ ows) {
  __shared__ u16 lds[24576];
  const int tid = threadIdx.x, w = tid >> 6, lane = tid & 63;
  const int l15 = lane & 15, g = lane >> 4;
  const int qb = blockIdx.x, bh = blockIdx.y;
  const int q0 = qb * 128;
  const u16* qbase = qkv + (size_t)bh * 131072;
  const u16* kbase = qkv + 8388608 + (size_t)bh * 131072;
  const u16* vtb = vt + (size_t)bh * 131072;

  short8 qf[2][2];
#pragma unroll
  for (int i = 0; i < 2; ++i)
#pragma unroll
    for (int ks = 0; ks < 2; ++ks)
      qf[i][ks] = *(const short8*)(qbase + ((size_t)(q0 + w * 32 + i * 16 + l15)) * 64 + ks * 32 + g * 8);

  // ---- pass 1: lsum + unnormalized PV ----
  u16* const pw = lds + 16384 + w * 2048;          // per-wave P [32][64] swz8
  float lsum[2] = {0.f, 0.f};
  f32x4 oacc[2][4];
#pragma unroll
  for (int i = 0; i < 2; ++i)
#pragma unroll
    for (int nd = 0; nd < 4; ++nd) oacc[i][nd] = (f32x4){0.f, 0.f, 0.f, 0.f};
  stage8<2>(kbase, 64, lds, tid);
  stage8<2>(vtb, 2048, lds + 8192, tid);
  __syncthreads();
  int buf = 0;
  for (int kt = 0; kt < 32; ++kt) {
    const u16* kb = lds + buf * 4096;
    const u16* vb = lds + 8192 + buf * 4096;
    if (kt < 31) {
      stage8<2>(kbase + (size_t)(kt + 1) * 4096, 64, lds + (buf ^ 1) * 4096, tid);
      stage8<2>(vtb + (size_t)(kt + 1) * 64, 2048, lds + 8192 + (buf ^ 1) * 4096, tid);
    }
    f32x4 acc[2][4];
#pragma unroll
    for (int i = 0; i < 2; ++i)
#pragma unroll
      for (int n = 0; n < 4; ++n) acc[i][n] = (f32x4){0.f, 0.f, 0.f, 0.f};
#pragma unroll
    for (int ks = 0; ks < 2; ++ks) {
      short8 kf[4];
#pragma unroll
      for (int n = 0; n < 4; ++n) kf[n] = ldsfrag8(kb, n * 16 + l15, ks * 4 + g);
      __builtin_amdgcn_s_setprio(1);
#pragma unroll
      for (int i = 0; i < 2; ++i)
#pragma unroll
        for (int n = 0; n < 4; ++n)
          acc[i][n] = mfma16(kf[n], qf[i][ks], acc[i][n]);
      __builtin_amdgcn_s_setprio(0);
    }
    // p = exp2(S) (UNNORMALIZED): accumulate row sums + pack bf16 -> LDS
#pragma unroll
    for (int i = 0; i < 2; ++i) {
      const int m = i * 16 + l15;
      f32x4 vs = {0.f, 0.f, 0.f, 0.f};
#pragma unroll
      for (int n = 0; n < 4; ++n) {
        f32x4 p4;
        p4[0] = __builtin_amdgcn_exp2f(acc[i][n][0]);
        p4[1] = __builtin_amdgcn_exp2f(acc[i][n][1]);
        p4[2] = __builtin_amdgcn_exp2f(acc[i][n][2]);
        p4[3] = __builtin_amdgcn_exp2f(acc[i][n][3]);
        vs += p4;
        u32x2 pk2;
        pk2[0] = cvtpk(p4[0], p4[1]);
        pk2[1] = cvtpk(p4[2], p4[3]);
        const int up = (n * 2 + (g >> 1)) ^ (m & 7);
        *(u32x2*)(pw + m * 64 + up * 8 + (g & 1) * 4) = pk2;
      }
      float s = (vs[0] + vs[1]) + (vs[2] + vs[3]);
      s += __shfl_xor(s, 16);
      s += __shfl_xor(s, 32);
      lsum[i] += s;
    }
    // PV: O_unnorm += P @ V
#pragma unroll
    for (int kp = 0; kp < 2; ++kp) {
      short8 ap[2], vf[4];
#pragma unroll
      for (int i = 0; i < 2; ++i) {
        int row = i * 16 + l15;
        ap[i] = *(const short8*)(pw + row * 64 + (((kp * 4 + g) ^ (row & 7)) * 8));
      }
#pragma unroll
      for (int nd = 0; nd < 4; ++nd) vf[nd] = ldsfrag8(vb, nd * 16 + l15, kp * 4 + g);
      __builtin_amdgcn_s_setprio(1);
#pragma unroll
      for (int i = 0; i < 2; ++i)
#pragma unroll
        for (int nd = 0; nd < 4; ++nd)
          oacc[i][nd] = mfma16(ap[i], vf[nd], oacc[i][nd]);
      __builtin_amdgcn_s_setprio(0);
    }
    __syncthreads();
    buf ^= 1;
  }
  float rl[2] = {1.0f / lsum[0], 1.0f / lsum[1]};

  // ---- O epilogue (between passes; frees oacc for pass 2) ----
  // oacc row = i*16 + g*4 + j, but rl is indexed by l15-row -> shuffle redistribute
  {
    const int b = bh >> 4, h = bh & 15;
#pragma unroll
    for (int i = 0; i < 2; ++i) {
      float rlj[4];
#pragma unroll
      for (int j = 0; j < 4; ++j) rlj[j] = __shfl(rl[i], g * 4 + j);
#pragma unroll
      for (int nd = 0; nd < 4; ++nd)
#pragma unroll
        for (int j = 0; j < 4; ++j) {
          int qrow = q0 + w * 32 + i * 16 + g * 4 + j;
          int d = nd * 16 + l15;
          ows[((size_t)qrow * 4 + b) * 1024 + (size_t)h * 64 + d] =
              f2bf(oacc[i][nd][j] * rlj[j]);
        }
    }
  }

  // ---- pass 2: KVBLK=128 pure store stream ----
  stage8<4>(kbase, 64, lds, tid);
  __syncthreads();
  buf = 0;
  float* arow = attn + ((size_t)bh * 2048 + q0 + w * 32) * 2048;
  for (int kt = 0; kt < 16; ++kt) {
    if (kt < 15) stage8<4>(kbase + (size_t)(kt + 1) * 8192, 64, lds + (buf ^ 1) * 8192, tid);
    const u16* kb = lds + buf * 8192;
    f32x4 acc[2][8];
#pragma unroll
    for (int i = 0; i < 2; ++i)
#pragma unroll
      for (int n = 0; n < 8; ++n) acc[i][n] = (f32x4){0.f, 0.f, 0.f, 0.f};
#pragma unroll
    for (int ks = 0; ks < 2; ++ks) {
      short8 kf[8];
#pragma unroll
      for (int n = 0; n < 8; ++n) kf[n] = ldsfrag8(kb, n * 16 + l15, ks * 4 + g);
      __builtin_amdgcn_s_setprio(1);
#pragma unroll
      for (int i = 0; i < 2; ++i)
#pragma unroll
        for (int n = 0; n < 8; ++n)
          acc[i][n] = mfma16(kf[n], qf[i][ks], acc[i][n]);
      __builtin_amdgcn_s_setprio(0);
    }
#pragma unroll
    for (int i = 0; i < 2; ++i) {
      const int m = i * 16 + l15;
#pragma unroll
      for (int n = 0; n < 8; ++n) {
        f32x4 p4;
        p4[0] = __builtin_amdgcn_exp2f(acc[i][n][0]) * rl[i];
        p4[1] = __builtin_amdgcn_exp2f(acc[i][n][1]) * rl[i];
        p4[2] = __builtin_amdgcn_exp2f(acc[i][n][2]) * rl[i];
        p4[3] = __builtin_amdgcn_exp2f(acc[i][n][3]) * rl[i];
        *(f32x4*)(arow + (size_t)m * 2048 + kt * 128 + n * 16 + g * 4) = p4;
      }
    }
    __syncthreads();
    buf ^= 1;
  }
}

// ---------------- GEMM2: out = O @ W_out^T + b (f32 out) ----------------
__global__ __launch_bounds__(256, 2) void gemm_out_kernel(
    const u16* __restrict__ abf, const u16* __restrict__ wbf,
    const float* __restrict__ bias, float* __restrict__ out) {
  __shared__ u16 pool[32768];
  f32x4 acc[4][4];
  int m0, n0;
  xcd_remap(m0, n0);
  gemm_core(abf, wbf, m0, n0, 1024, pool, pool + 16384, acc);
  const int tid = threadIdx.x, lane = tid & 63, w = tid >> 6;
  const int l15 = lane & 15, g = lane >> 4;
  const int wr = w >> 1, wc = w & 1;
#pragma unroll
  for (int n = 0; n < 4; ++n) {
    int ng = n0 + wc * 64 + n * 16 + l15;
    float bv = bias[ng];
#pragma unroll
    for (int i = 0; i < 4; ++i)
#pragma unroll
      for (int j = 0; j < 4; ++j) {
        int mg = m0 + wr * 64 + i * 16 + g * 4 + j;
        out[(size_t)mg * 1024 + ng] = acc[i][n][j] + bv;
      }
  }
}

extern "C" void kernel_launch(void* const* d_in, const int* in_sizes, int n_in,
                              void* d_out, int out_size, void* d_ws, size_t ws_size,
                              hipStream_t stream) {
  const float* x     = (const float*)d_in[0];
  const float* w_in  = (const float*)d_in[1];
  const float* b_in  = (const float*)d_in[2];
  const float* w_out = (const float*)d_in[3];
  const float* b_out = (const float*)d_in[4];
  float* out  = (float*)d_out;
  float* attn = out + 8388608;              // [64][2048][2048]

  char* ws = (char*)d_ws;
  u16* qkv  = (u16*)ws;                      // [2][64][2048][64] bf16 (q,k)
  u16* vt   = (u16*)(ws + 50331648);         // [64][64][2048]
  u16* xbf  = (u16*)(ws + 67108864);         // [8192][1024] (reused as O)
  u16* wibf = (u16*)(ws + 83886080);         // [3072][1024]
  u16* wobf = (u16*)(ws + 90177536);         // [1024][1024]
  u16* ows  = xbf;                           // reuse after gemm1 consumed xbf

  convert_kernel<<<12288, 256, 0, stream>>>(x, w_in, w_out, xbf, wibf, wobf);
  gemm_qkv_kernel<<<dim3(64, 24), 256, 0, stream>>>(xbf, wibf, b_in, qkv, vt);
  attn_kernel<<<dim3(16, 64), 256, 0, stream>>>(qkv, vt, attn, ows);
  gemm_out_kernel<<<dim3(64, 8), 256, 0, stream>>>(ows, wobf, b_out, out);
}

// Round 10
// 372.771 us; speedup vs baseline: 1.4540x; 1.0483x over previous
//
#include <hip/hip_runtime.h>

#define S_LEN 2048

typedef __attribute__((ext_vector_type(8))) short short8;
typedef __attribute__((ext_vector_type(4))) float f32x4;
typedef __attribute__((ext_vector_type(2))) unsigned int u32x2;
typedef unsigned short u16;
typedef unsigned int u32;
typedef __attribute__((ext_vector_type(4))) unsigned short us4;

__device__ __forceinline__ u16 f2bf(float f) {
  union { float f; u32 u; } v; v.f = f;
  u32 r = v.u + 0x7FFFu + ((v.u >> 16) & 1u);
  return (u16)(r >> 16);
}

// packed f32x2 -> bf16x2 (RNE), 1 VALU inst
__device__ __forceinline__ u32 cvtpk(float lo, float hi) {
  u32 r;
  asm("v_cvt_pk_bf16_f32 %0, %1, %2" : "=v"(r) : "v"(lo), "v"(hi));
  return r;
}

__device__ __forceinline__ void gload_lds16(const u16* g, u16* l) {
  __builtin_amdgcn_global_load_lds(
      (const __attribute__((address_space(1))) u32*)g,
      (__attribute__((address_space(3))) u32*)l, 16, 0, 0);
}

__device__ __forceinline__ f32x4 mfma16(short8 a, short8 b, f32x4 c) {
  return __builtin_amdgcn_mfma_f32_16x16x32_bf16(a, b, c, 0, 0, 0);
}

// Stage NL*256 16B-units of an 8-unit-per-row tile into linear LDS with
// 3-bit row-XOR source pre-swizzle (linear dest + inverse-swz source).
template <int NL>
__device__ __forceinline__ void stage8(const u16* __restrict__ gbase, int row_stride,
                                       u16* lds, int tid) {
#pragma unroll
  for (int p = 0; p < NL; ++p) {
    int L = tid + p * 256;
    int r = L >> 3, up = L & 7;
    int u = up ^ (r & 7);
    gload_lds16(gbase + (size_t)r * row_stride + u * 8, lds + (size_t)L * 8);
  }
}
__device__ __forceinline__ short8 ldsfrag8(const u16* lds, int row, int u) {
  int up = u ^ (row & 7);
  return *(const short8*)(lds + (size_t)row * 64 + up * 8);
}

// ---------------- convert f32 -> bf16 (x, in_proj_w, out_proj_w) ----------------
__global__ __launch_bounds__(256) void convert_kernel(
    const float* __restrict__ x, const float* __restrict__ wi, const float* __restrict__ wo,
    u16* __restrict__ xbf, u16* __restrict__ wibf, u16* __restrict__ wobf) {
  int idx = blockIdx.x * 256 + threadIdx.x;   // each handles 4 floats
  const float* src; u16* dst; int off;
  if (idx < 2097152)            { src = x;  dst = xbf;  off = idx; }
  else if (idx < 2883584)       { src = wi; dst = wibf; off = idx - 2097152; }
  else                          { src = wo; dst = wobf; off = idx - 2883584; }
  f32x4 v = *(const f32x4*)(src + (size_t)off * 4);
  us4 r;
#pragma unroll
  for (int j = 0; j < 4; ++j) r[j] = f2bf(v[j]);
  *(us4*)(dst + (size_t)off * 4) = r;
}

// ---------------- shared 128x128 GEMM core: C = A[M,K] * B[N,K]^T ----------------
__device__ __forceinline__ void gemm_core(const u16* __restrict__ A, const u16* __restrict__ B,
                                          int m0, int n0, int K,
                                          u16* aL, u16* bL, f32x4 acc[4][4]) {
  const int tid = threadIdx.x;
  const int lane = tid & 63, w = tid >> 6;
  const int l15 = lane & 15, g = lane >> 4;
  const int wr = w >> 1, wc = w & 1;
#pragma unroll
  for (int i = 0; i < 4; ++i)
#pragma unroll
    for (int n = 0; n < 4; ++n) acc[i][n] = (f32x4){0.f, 0.f, 0.f, 0.f};
  const int nK = K >> 6;
  stage8<4>(A + (size_t)m0 * K, K, aL, tid);
  stage8<4>(B + (size_t)n0 * K, K, bL, tid);
  __syncthreads();
  int buf = 0;
  for (int kt = 0; kt < nK; ++kt) {
    if (kt + 1 < nK) {
      stage8<4>(A + (size_t)m0 * K + (kt + 1) * 64, K, aL + (buf ^ 1) * 8192, tid);
      stage8<4>(B + (size_t)n0 * K + (kt + 1) * 64, K, bL + (buf ^ 1) * 8192, tid);
    }
    const u16* ab = aL + buf * 8192;
    const u16* bb = bL + buf * 8192;
#pragma unroll
    for (int ks = 0; ks < 2; ++ks) {
      short8 af[4], bf[4];
#pragma unroll
      for (int i = 0; i < 4; ++i) af[i] = ldsfrag8(ab, wr * 64 + i * 16 + l15, ks * 4 + g);
#pragma unroll
      for (int n = 0; n < 4; ++n) bf[n] = ldsfrag8(bb, wc * 64 + n * 16 + l15, ks * 4 + g);
      __builtin_amdgcn_s_setprio(1);
#pragma unroll
      for (int i = 0; i < 4; ++i)
#pragma unroll
        for (int n = 0; n < 4; ++n)
          acc[i][n] = mfma16(af[i], bf[n], acc[i][n]);
      __builtin_amdgcn_s_setprio(0);
    }
    __syncthreads();
    buf ^= 1;
  }
}

// XCD-aware m-strip remap: each XCD gets (nM/8) m-tiles x all n-tiles, n fastest
// (A-panel stays hot in the XCD's L2). Requires gridDim.x % 8 == 0.
__device__ __forceinline__ void xcd_remap(int& m0, int& n0) {
  int nM = gridDim.x, nN = gridDim.y;
  int id = blockIdx.y * nM + blockIdx.x;
  int xcd = id & 7, local = id >> 3;
  int mt = xcd * (nM >> 3) + local / nN;
  int nt = local % nN;
  m0 = mt * 128;
  n0 = nt * 128;
}

// ---------------- GEMM1: qkv = x @ W_in^T + b -> q,k scatter + V^T fused ----------------
// q additionally scaled by hd^-0.5 * log2(e)  (folds softmax's base-2 conversion)
__global__ __launch_bounds__(256, 2) void gemm_qkv_kernel(
    const u16* __restrict__ xbf, const u16* __restrict__ wbf,
    const float* __restrict__ bias, u16* __restrict__ qkv, u16* __restrict__ vt) {
  __shared__ u16 pool[32768];          // 64 KB: gemm dbuf; reused as C_lds
  f32x4 acc[4][4];
  int m0, n0;
  xcd_remap(m0, n0);
  gemm_core(xbf, wbf, m0, n0, 1024, pool, pool + 16384, acc);
  const int tid = threadIdx.x, lane = tid & 63, w = tid >> 6;
  const int l15 = lane & 15, g = lane >> 4;
  const int wr = w >> 1, wc = w & 1;
  const int sec = n0 >> 10;                        // 0=q 1=k 2=v
  const float scale = (sec == 0) ? 0.18033688011112042f : 1.0f;  // 0.125*log2(e)
  u16* cl = pool;
#pragma unroll
  for (int n = 0; n < 4; ++n) {
    int c = wc * 64 + n * 16 + l15;
    float bv = bias[n0 + c];
#pragma unroll
    for (int i = 0; i < 4; ++i)
#pragma unroll
      for (int j = 0; j < 4; ++j) {
        int mrow = wr * 64 + i * 16 + g * 4 + j;
        cl[mrow * 132 + c] = f2bf((acc[i][n][j] + bv) * scale);
      }
  }
  __syncthreads();
  const int h0 = (n0 & 1023) >> 6;
  if (sec < 2) {
    u16* dst = qkv + (size_t)sec * 8388608;
#pragma unroll
    for (int rep = 0; rep < 8; ++rep) {
      int chunk = rep * 256 + tid;
      int mrow = chunk >> 4, c = (chunk & 15) << 3;
      short8 vv = *(const short8*)(cl + mrow * 132 + c);
      int mg = m0 + mrow;
      int s = mg >> 2, b = mg & 3;
      int h = h0 + (c >> 6), d = c & 63;
      *(short8*)(dst + (((size_t)(b * 16 + h)) * 2048 + s) * 64 + d) = vv;
    }
  } else {
#pragma unroll
    for (int rep = 0; rep < 8; ++rep) {
      int chunk = rep * 256 + tid;
      int col = chunk >> 4;
      int b = (chunk >> 2) & 3;
      int sc = (chunk & 3) << 3;
      short8 vv;
#pragma unroll
      for (int t = 0; t < 8; ++t)
        vv[t] = (short)cl[(((sc + t) << 2) | b) * 132 + col];
      int h = h0 + (col >> 6), d = col & 63;
      *(short8*)(vt + (size_t)(b * 16 + h) * 131072 + (size_t)d * 2048 + (m0 >> 2) + sc) = vv;
    }
  }
}

// ---------------- fused attention ----------------
// Swapped QK^T: acc[i][n][j] = S[q = w*32+i*16+l15][k = n*16+g*4+j] (log2-domain, q pre-scaled)
// pass 1 (KVBLK=64): QK + exp2 + explicit f32 row-sum (l15-indexed) + PV with
//   UNNORMALIZED P (flash late-norm). O *= 1/l (shuffle-redistributed) stored between passes.
// pass 2 (KVBLK=128): pure store stream; acc init = -log2(lsum) folds normalization
//   into the exp2 argument (lsum[i] is l15-indexed == pass-2 acc rows; no shuffle).
__global__ __launch_bounds__(256, 3) void attn_kernel(
    const u16* __restrict__ qkv, const u16* __restrict__ vt,
    float* __restrict__ attn, u16* __restrict__ ows) {
  __shared__ u16 lds[24576];
  const int tid = threadIdx.x, w = tid >> 6, lane = tid & 63;
  const int l15 = lane & 15, g = lane >> 4;
  // XCD-chunked remap: 8 consecutive bh per XCD, qb fastest -> K/V L2-resident
  const int id = blockIdx.y * gridDim.x + blockIdx.x;
  const int xcd = id & 7, t = id >> 3;
  const int bh = xcd * 8 + (t >> 4);
  const int qb = t & 15;
  const int q0 = qb * 128;
  const u16* qbase = qkv + (size_t)bh * 131072;
  const u16* kbase = qkv + 8388608 + (size_t)bh * 131072;
  const u16* vtb = vt + (size_t)bh * 131072;

  short8 qf[2][2];
#pragma unroll
  for (int i = 0; i < 2; ++i)
#pragma unroll
    for (int ks = 0; ks < 2; ++ks)
      qf[i][ks] = *(const short8*)(qbase + ((size_t)(q0 + w * 32 + i * 16 + l15)) * 64 + ks * 32 + g * 8);

  // ---- pass 1: explicit f32 lsum + unnormalized PV ----
  u16* const pw = lds + 16384 + w * 2048;          // per-wave P [32][64] swz8
  float lsum[2] = {0.f, 0.f};
  f32x4 oacc[2][4];
#pragma unroll
  for (int i = 0; i < 2; ++i)
#pragma unroll
    for (int nd = 0; nd < 4; ++nd) oacc[i][nd] = (f32x4){0.f, 0.f, 0.f, 0.f};
  stage8<2>(kbase, 64, lds, tid);
  stage8<2>(vtb, 2048, lds + 8192, tid);
  __syncthreads();
  int buf = 0;
  for (int kt = 0; kt < 32; ++kt) {
    const u16* kb = lds + buf * 4096;
    const u16* vb = lds + 8192 + buf * 4096;
    if (kt < 31) {
      stage8<2>(kbase + (size_t)(kt + 1) * 4096, 64, lds + (buf ^ 1) * 4096, tid);
      stage8<2>(vtb + (size_t)(kt + 1) * 64, 2048, lds + 8192 + (buf ^ 1) * 4096, tid);
    }
    f32x4 acc[2][4];
#pragma unroll
    for (int i = 0; i < 2; ++i)
#pragma unroll
      for (int n = 0; n < 4; ++n) acc[i][n] = (f32x4){0.f, 0.f, 0.f, 0.f};
#pragma unroll
    for (int ks = 0; ks < 2; ++ks) {
      short8 kf[4];
#pragma unroll
      for (int n = 0; n < 4; ++n) kf[n] = ldsfrag8(kb, n * 16 + l15, ks * 4 + g);
      __builtin_amdgcn_s_setprio(1);
#pragma unroll
      for (int i = 0; i < 2; ++i)
#pragma unroll
        for (int n = 0; n < 4; ++n)
          acc[i][n] = mfma16(kf[n], qf[i][ks], acc[i][n]);
      __builtin_amdgcn_s_setprio(0);
    }
    // p = exp2(S) UNNORMALIZED: row-sum (f32) + pack bf16 -> LDS
#pragma unroll
    for (int i = 0; i < 2; ++i) {
      const int m = i * 16 + l15;
      f32x4 vs = {0.f, 0.f, 0.f, 0.f};
#pragma unroll
      for (int n = 0; n < 4; ++n) {
        f32x4 p4;
        p4[0] = __builtin_amdgcn_exp2f(acc[i][n][0]);
        p4[1] = __builtin_amdgcn_exp2f(acc[i][n][1]);
        p4[2] = __builtin_amdgcn_exp2f(acc[i][n][2]);
        p4[3] = __builtin_amdgcn_exp2f(acc[i][n][3]);
        vs += p4;
        u32x2 pk2;
        pk2[0] = cvtpk(p4[0], p4[1]);
        pk2[1] = cvtpk(p4[2], p4[3]);
        const int up = (n * 2 + (g >> 1)) ^ (m & 7);
        *(u32x2*)(pw + m * 64 + up * 8 + (g & 1) * 4) = pk2;
      }
      float s = (vs[0] + vs[1]) + (vs[2] + vs[3]);
      s += __shfl_xor(s, 16);
      s += __shfl_xor(s, 32);
      lsum[i] += s;
    }
    // PV: O_unnorm += P @ V
#pragma unroll
    for (int kp = 0; kp < 2; ++kp) {
      short8 ap[2], vf[4];
#pragma unroll
      for (int i = 0; i < 2; ++i) {
        int row = i * 16 + l15;
        ap[i] = *(const short8*)(pw + row * 64 + (((kp * 4 + g) ^ (row & 7)) * 8));
      }
#pragma unroll
      for (int nd = 0; nd < 4; ++nd) vf[nd] = ldsfrag8(vb, nd * 16 + l15, kp * 4 + g);
      __builtin_amdgcn_s_setprio(1);
#pragma unroll
      for (int i = 0; i < 2; ++i)
#pragma unroll
        for (int nd = 0; nd < 4; ++nd)
          oacc[i][nd] = mfma16(ap[i], vf[nd], oacc[i][nd]);
      __builtin_amdgcn_s_setprio(0);
    }
    __syncthreads();
    buf ^= 1;
  }
  float rl[2] = {1.0f / lsum[0], 1.0f / lsum[1]};

  // ---- O epilogue (between passes; frees oacc for pass 2) ----
  // oacc row = i*16 + g*4 + j; rl is l15-indexed -> shuffle redistribute (R8-proven)
  {
    const int b = bh >> 4, h = bh & 15;
#pragma unroll
    for (int i = 0; i < 2; ++i) {
      float rlj[4];
#pragma unroll
      for (int j = 0; j < 4; ++j) rlj[j] = __shfl(rl[i], g * 4 + j);
#pragma unroll
      for (int nd = 0; nd < 4; ++nd)
#pragma unroll
        for (int j = 0; j < 4; ++j) {
          int qrow = q0 + w * 32 + i * 16 + g * 4 + j;
          int d = nd * 16 + l15;
          ows[((size_t)qrow * 4 + b) * 1024 + (size_t)h * 64 + d] =
              f2bf(oacc[i][nd][j] * rlj[j]);
        }
    }
  }

  // pass-2 fold: lsum[i] is already indexed by q-row i*16+l15 == pass-2 acc rows
  float linit[2] = {-__log2f(lsum[0]), -__log2f(lsum[1])};

  // ---- pass 2: KVBLK=128 pure store stream; normalization folded into exp2 arg ----
  stage8<4>(kbase, 64, lds, tid);
  __syncthreads();
  buf = 0;
  float* arow = attn + ((size_t)bh * 2048 + q0 + w * 32) * 2048;
  for (int kt = 0; kt < 16; ++kt) {
    if (kt < 15) stage8<4>(kbase + (size_t)(kt + 1) * 8192, 64, lds + (buf ^ 1) * 8192, tid);
    const u16* kb = lds + buf * 8192;
    f32x4 acc[2][8];
#pragma unroll
    for (int i = 0; i < 2; ++i)
#pragma unroll
      for (int n = 0; n < 8; ++n)
        acc[i][n] = (f32x4){linit[i], linit[i], linit[i], linit[i]};
#pragma unroll
    for (int ks = 0; ks < 2; ++ks) {
      short8 kf[8];
#pragma unroll
      for (int n = 0; n < 8; ++n) kf[n] = ldsfrag8(kb, n * 16 + l15, ks * 4 + g);
      __builtin_amdgcn_s_setprio(1);
#pragma unroll
      for (int i = 0; i < 2; ++i)
#pragma unroll
        for (int n = 0; n < 8; ++n)
          acc[i][n] = mfma16(kf[n], qf[i][ks], acc[i][n]);
      __builtin_amdgcn_s_setprio(0);
    }
#pragma unroll
    for (int i = 0; i < 2; ++i) {
      const int m = i * 16 + l15;
#pragma unroll
      for (int n = 0; n < 8; ++n) {
        f32x4 p4;
        p4[0] = __builtin_amdgcn_exp2f(acc[i][n][0]);
        p4[1] = __builtin_amdgcn_exp2f(acc[i][n][1]);
        p4[2] = __builtin_amdgcn_exp2f(acc[i][n][2]);
        p4[3] = __builtin_amdgcn_exp2f(acc[i][n][3]);
        *(f32x4*)(arow + (size_t)m * 2048 + kt * 128 + n * 16 + g * 4) = p4;
      }
    }
    __syncthreads();
    buf ^= 1;
  }
}

// ---------------- GEMM2: out = O @ W_out^T + b (f32 out) ----------------
__global__ __launch_bounds__(256, 2) void gemm_out_kernel(
    const u16* __restrict__ abf, const u16* __restrict__ wbf,
    const float* __restrict__ bias, float* __restrict__ out) {
  __shared__ u16 pool[32768];
  f32x4 acc[4][4];
  int m0, n0;
  xcd_remap(m0, n0);
  gemm_core(abf, wbf, m0, n0, 1024, pool, pool + 16384, acc);
  const int tid = threadIdx.x, lane = tid & 63, w = tid >> 6;
  const int l15 = lane & 15, g = lane >> 4;
  const int wr = w >> 1, wc = w & 1;
#pragma unroll
  for (int n = 0; n < 4; ++n) {
    int ng = n0 + wc * 64 + n * 16 + l15;
    float bv = bias[ng];
#pragma unroll
    for (int i = 0; i < 4; ++i)
#pragma unroll
      for (int j = 0; j < 4; ++j) {
        int mg = m0 + wr * 64 + i * 16 + g * 4 + j;
        out[(size_t)mg * 1024 + ng] = acc[i][n][j] + bv;
      }
  }
}

extern "C" void kernel_launch(void* const* d_in, const int* in_sizes, int n_in,
                              void* d_out, int out_size, void* d_ws, size_t ws_size,
                              hipStream_t stream) {
  const float* x     = (const float*)d_in[0];
  const float* w_in  = (const float*)d_in[1];
  const float* b_in  = (const float*)d_in[2];
  const float* w_out = (const float*)d_in[3];
  const float* b_out = (const float*)d_in[4];
  float* out  = (float*)d_out;
  float* attn = out + 8388608;              // [64][2048][2048]

  char* ws = (char*)d_ws;
  u16* qkv  = (u16*)ws;                      // [2][64][2048][64] bf16 (q,k)
  u16* vt   = (u16*)(ws + 50331648);         // [64][64][2048]
  u16* xbf  = (u16*)(ws + 67108864);         // [8192][1024] (reused as O)
  u16* wibf = (u16*)(ws + 83886080);         // [3072][1024]
  u16* wobf = (u16*)(ws + 90177536);         // [1024][1024]
  u16* ows  = xbf;                           // reuse after gemm1 consumed xbf

  convert_kernel<<<12288, 256, 0, stream>>>(x, w_in, w_out, xbf, wibf, wobf);
  gemm_qkv_kernel<<<dim3(64, 24), 256, 0, stream>>>(xbf, wibf, b_in, qkv, vt);
  attn_kernel<<<dim3(16, 64), 256, 0, stream>>>(qkv, vt, attn, ows);
  gemm_out_kernel<<<dim3(64, 8), 256, 0, stream>>>(ows, wobf, b_out, out);
}